// Round 4
// baseline (498.934 us; speedup 1.0000x reference)
//
#include <hip/hip_runtime.h>

typedef __attribute__((ext_vector_type(4)))  float f32x4;
typedef __attribute__((ext_vector_type(16))) float f32x16;
typedef __attribute__((ext_vector_type(8)))  short s16x8;
typedef __attribute__((ext_vector_type(4)))  short s16x4;

// B=512, T=256, E=384, H=64.

__device__ inline short f2bf(float f){
  unsigned u = __float_as_uint(f);
  u = u + 0x7fffu + ((u >> 16) & 1u);   // round-to-nearest-even
  return (short)(u >> 16);
}

// ---------------- Kernel 0: Wt[n][k] = W_{n/64}[k][n%64]  (bf16) ----------------
__global__ void wt_prep_kernel(const float* __restrict__ Wq, const float* __restrict__ Wk,
                               const float* __restrict__ Wv, short* __restrict__ Wt){
  int o = blockIdx.x * 256 + threadIdx.x;
  if (o >= 192*384) return;
  int n = o / 384, k = o - n*384;
  const float* W = (n < 64) ? Wq : (n < 128) ? Wk : Wv;
  Wt[o] = f2bf(W[k*64 + (n & 63)]);
}

// ---------------- Fused QKV-projection + causal attention (v2) ----------------
// 1 block = 1 batch, 8 waves, __launch_bounds__(512,4) -> <=128 regs, and
// LDS = 72 KB (Q,K only; V goes to global; P aliases Qs) -> 2 blocks/CU.
// Phase 1: wave w, col-half (w&1)*96 (3 frags = 48 AGPR), 2 row-group iters
// of 32 rows; operand-swapped 32x32x16 MFMA, barrier-free K-loop, 1-step
// x prefetch. Phase 2: wave w owns q-frags {w, 15-w} (balanced causal);
// all Q A-frags preloaded to regs, then Qs LDS is reused as P scratch.
__global__ __launch_bounds__(512, 4) void fused_kernel(const float* __restrict__ x,
                             const short* __restrict__ Wt, short* __restrict__ Vg,
                             float* __restrict__ out){
  __shared__ __align__(16) short Qs[256*72];    // 36864 B (stride 144B: 16B-aligned rows)
  __shared__ __align__(16) short Ks[256*72];    // 36864 B

  const int tid  = threadIdx.x;
  const int w    = tid >> 6, lane = tid & 63;
  const int l31  = lane & 31, hh = lane >> 5;
  const int b    = blockIdx.x;
  const int ch   = (w & 1) * 96;                // this wave's column half
  short* Vb = Vg + (long)b*64*256;              // V transposed [h][t] in global scratch

  // ================= Phase 1: QKV projection =================
  for (int j = 0; j < 2; ++j){
    const int rg   = (w >> 1) + j*4;            // row group: 8 groups x 32 rows
    const int trow = rg*32 + l31;
    const float* xp = x + ((long)b*256 + trow)*384 + hh*8;

    f32x16 acc[3];
    #pragma unroll
    for (int c = 0; c < 3; ++c)
      #pragma unroll
      for (int q = 0; q < 16; ++q) acc[c][q] = 0.0f;

    float4 c0 = *(const float4*)xp;
    float4 c1 = *(const float4*)(xp + 4);
    #pragma unroll
    for (int s = 0; s < 24; ++s){
      float4 n0, n1;
      if (s < 23){
        n0 = *(const float4*)(xp + (s+1)*16);
        n1 = *(const float4*)(xp + (s+1)*16 + 4);
      }
      s16x8 bx;                                 // B[k][n=row]
      bx[0]=f2bf(c0.x); bx[1]=f2bf(c0.y); bx[2]=f2bf(c0.z); bx[3]=f2bf(c0.w);
      bx[4]=f2bf(c1.x); bx[5]=f2bf(c1.y); bx[6]=f2bf(c1.z); bx[7]=f2bf(c1.w);
      #pragma unroll
      for (int c = 0; c < 3; ++c){              // A[m=outcol][k] from Wt (L1/L2-hot)
        s16x8 wa = *(const s16x8*)(Wt + (ch + c*32 + l31)*384 + s*16 + hh*8);
        acc[c] = __builtin_amdgcn_mfma_f32_32x32x16_bf16(wa, bx, acc[c], 0, 0, 0);
      }
      c0 = n0; c1 = n1;
    }

    // Epilogue: C col(n)=row=l31, m=(reg&3)+8*(reg>>2)+4*hh = outcol offset
    #pragma unroll
    for (int c = 0; c < 3; ++c){
      const int n0 = ch + c*32;
      if (n0 < 128){                            // Q (n0 0,32) or K (n0 64,96)
        short* dst = (n0 < 64) ? (Qs + trow*72 + n0) : (Ks + trow*72 + (n0 - 64));
        #pragma unroll
        for (int g = 0; g < 4; ++g){
          s16x4 v;
          #pragma unroll
          for (int i = 0; i < 4; ++i) v[i] = f2bf(acc[c][g*4 + i]);
          *(s16x4*)(dst + 8*g + 4*hh) = v;
        }
      } else {                                  // V -> global Vb[h][t]
        #pragma unroll
        for (int reg = 0; reg < 16; ++reg){
          const int h = (n0 - 128) + (reg & 3) + 8*(reg >> 2) + 4*hh;
          Vb[h*256 + trow] = f2bf(acc[c][reg]);
        }
      }
    }
  }
  __syncthreads();

  // ================= Phase 2: causal attention =================
  const int l15 = lane & 15, quad = lane >> 4;
  float* ob = out + (long)b*256*64;

  // Preload Q A-frags for both q-frag iterations, then Qs becomes P scratch.
  const int Fs[2] = { w, 15 - w };
  s16x8 qa[2][2];
  #pragma unroll
  for (int it = 0; it < 2; ++it){
    qa[it][0] = *(const s16x8*)(Qs + (Fs[it]*16 + l15)*72 + quad*8);
    qa[it][1] = *(const s16x8*)(Qs + (Fs[it]*16 + l15)*72 + 32 + quad*8);
  }
  __syncthreads();
  short* Pw = Qs + w*1280;                      // 16x40 shorts per wave, aliased into Qs

  #pragma unroll
  for (int it = 0; it < 2; ++it){
    const int F  = Fs[it];
    const int qb = F*16;
    const int NF = F + 1;                       // causal key-frags (1..16)
    const int NS = (NF + 1) >> 1;               // 32-key PV steps
    const s16x8 qf0 = qa[it][0], qf1 = qa[it][1];

    f32x4 sc[16];
    #pragma unroll
    for (int f = 0; f < 16; ++f){
      f32x4 a;
      #pragma unroll
      for (int r = 0; r < 4; ++r) a[r] = 0.0f;
      if (f < NF){
        const short* kp = Ks + (f*16 + l15)*72 + quad*8;  // B[k=h][n=key]
        s16x8 k0v = *(const s16x8*)kp;
        s16x8 k1v = *(const s16x8*)(kp + 32);
        a = __builtin_amdgcn_mfma_f32_16x16x32_bf16(qf0, k0v, a, 0, 0, 0);
        a = __builtin_amdgcn_mfma_f32_16x16x32_bf16(qf1, k1v, a, 0, 0, 0);
      }
      sc[f] = a;
    }

    // softmax: C col=key=f*16+l15, row=q=quad*4+r
    float mx[4], sm[4];
    #pragma unroll
    for (int r = 0; r < 4; ++r) mx[r] = -3.0e38f;
    #pragma unroll
    for (int f = 0; f < 16; ++f){
      if (f < NF){
        const int key = f*16 + l15;
        #pragma unroll
        for (int r = 0; r < 4; ++r){
          const int qg = qb + quad*4 + r;
          float s = sc[f][r] * 0.125f;          // d^-0.5, H=64
          s = (key <= qg) ? s : -1.0e30f;
          sc[f][r] = s;
          mx[r] = fmaxf(mx[r], s);
        }
      }
    }
    #pragma unroll
    for (int r = 0; r < 4; ++r){
      #pragma unroll
      for (int off = 1; off < 16; off <<= 1) mx[r] = fmaxf(mx[r], __shfl_xor(mx[r], off, 16));
    }
    #pragma unroll
    for (int r = 0; r < 4; ++r) sm[r] = 0.0f;
    #pragma unroll
    for (int f = 0; f < 16; ++f){
      if (f < NF){
        #pragma unroll
        for (int r = 0; r < 4; ++r){
          float p = exp2f((sc[f][r] - mx[r]) * 1.44269504f);
          sc[f][r] = p;
          sm[r] += p;
        }
      }
    }
    #pragma unroll
    for (int r = 0; r < 4; ++r){
      #pragma unroll
      for (int off = 1; off < 16; off <<= 1) sm[r] += __shfl_xor(sm[r], off, 16);
    }

    // PV: A = P (LDS round-trip C->A layout), B = V frags from global (L2-hot)
    f32x4 o[4];
    #pragma unroll
    for (int h0 = 0; h0 < 4; ++h0)
      #pragma unroll
      for (int r = 0; r < 4; ++r) o[h0][r] = 0.0f;

    #pragma unroll
    for (int ks = 0; ks < 8; ++ks){
      if (ks < NS){
        #pragma unroll
        for (int fi = 0; fi < 2; ++fi){
          const int f = 2*ks + fi;
          #pragma unroll
          for (int r = 0; r < 4; ++r){
            short v = 0;
            if (f < NF) v = f2bf(sc[f][r]);
            Pw[(quad*4 + r)*40 + fi*16 + l15] = v;
          }
        }
        s16x8 pf = *(const s16x8*)(Pw + l15*40 + quad*8);   // A[m=q][k]
        #pragma unroll
        for (int h0 = 0; h0 < 4; ++h0){
          s16x8 vf = *(const s16x8*)(Vb + (h0*16 + l15)*256 + ks*32 + quad*8);
          o[h0] = __builtin_amdgcn_mfma_f32_16x16x32_bf16(pf, vf, o[h0], 0, 0, 0);
        }
      }
    }

    #pragma unroll
    for (int r = 0; r < 4; ++r){
      const float inv = 1.0f / sm[r];
      #pragma unroll
      for (int h0 = 0; h0 < 4; ++h0)
        ob[(qb + quad*4 + r)*64 + h0*16 + l15] = o[h0][r] * inv;
    }
  }
}

extern "C" void kernel_launch(void* const* d_in, const int* in_sizes, int n_in,
                              void* d_out, int out_size, void* d_ws, size_t ws_size,
                              hipStream_t stream){
  const float* x  = (const float*)d_in[0];
  const float* Wq = (const float*)d_in[1];
  const float* Wk = (const float*)d_in[2];
  const float* Wv = (const float*)d_in[3];
  float* out = (float*)d_out;

  char* ws = (char*)d_ws;
  short* Wt = (short*)ws;                         // 147456 B
  short* Vg = (short*)(ws + 147456);              // 512*64*256*2 = 16.78 MB

  hipLaunchKernelGGL(wt_prep_kernel, dim3(288), dim3(256), 0, stream, Wq, Wk, Wv, Wt);
  hipLaunchKernelGGL(fused_kernel,   dim3(512), dim3(512), 0, stream, x, Wt, Vg, out);
}

// Round 5
// 468.999 us; speedup vs baseline: 1.0638x; 1.0638x over previous
//
#include <hip/hip_runtime.h>

typedef __attribute__((ext_vector_type(4)))  float f32x4;
typedef __attribute__((ext_vector_type(16))) float f32x16;
typedef __attribute__((ext_vector_type(8)))  short s16x8;
typedef __attribute__((ext_vector_type(4)))  short s16x4;

// B=512, T=256, E=384, H=64.  M = B*T = 131072 rows.

__device__ inline short f2bf(float f){
  unsigned u = __float_as_uint(f);
  u = u + 0x7fffu + ((u >> 16) & 1u);   // round-to-nearest-even
  return (short)(u >> 16);
}

// ---------------- Kernel 0: Wt[n][k] = W_{n/64}[k][n%64]  (bf16) ----------------
__global__ void wt_prep_kernel(const float* __restrict__ Wq, const float* __restrict__ Wk,
                               const float* __restrict__ Wv, short* __restrict__ Wt){
  int o = blockIdx.x * 256 + threadIdx.x;
  if (o >= 192*384) return;
  int n = o / 384, k = o - n*384;
  const float* W = (n < 64) ? Wq : (n < 128) ? Wk : Wv;
  Wt[o] = f2bf(W[k*64 + (n & 63)]);
}

// ---------------- Kernel 1: QKV projection v2 (barrier-free, no LDS) ----------
// Operand-swapped 32x32x16 MFMA: A = Wt cols (L1/L2-hot, shared by all waves),
// B = x rows (contiguous per row). Wave tile = 32 rows x 96 cols -> acc[3]
// (48 AGPR), ~50 VGPR -> 4 waves/SIMD under __launch_bounds__(256,4).
// Block = 4 waves = 64 rows x 192 cols. Grid 2048. No __syncthreads anywhere:
// x loads pipeline freely across the whole K-loop (the R2 version drained
// vmcnt(0) 12x per block at LDS barriers).
__global__ __launch_bounds__(256, 4) void proj_kernel(const float* __restrict__ x,
                            const short* __restrict__ Wt,
                            short* __restrict__ Q, short* __restrict__ K,
                            short* __restrict__ Vt){
  const int tid  = threadIdx.x;
  const int w    = tid >> 6, lane = tid & 63;
  const int l31  = lane & 31, hh = lane >> 5;
  const int ch   = (w & 1) * 96;                 // column half: 0..95 or 96..191
  const long trow = (long)blockIdx.x*64 + (w >> 1)*32 + l31;
  const float* xp = x + trow*384 + hh*8;

  f32x16 acc[3];
  #pragma unroll
  for (int c = 0; c < 3; ++c)
    #pragma unroll
    for (int q = 0; q < 16; ++q) acc[c][q] = 0.0f;

  float4 c0 = *(const float4*)xp;
  float4 c1 = *(const float4*)(xp + 4);
  #pragma unroll
  for (int s = 0; s < 24; ++s){                  // K-steps of 16 (k = s*16 + hh*8 + j)
    float4 n0, n1;
    if (s < 23){
      n0 = *(const float4*)(xp + (s+1)*16);
      n1 = *(const float4*)(xp + (s+1)*16 + 4);
    }
    s16x8 bx;                                    // B[k][n=row]: lane l31 = row
    bx[0]=f2bf(c0.x); bx[1]=f2bf(c0.y); bx[2]=f2bf(c0.z); bx[3]=f2bf(c0.w);
    bx[4]=f2bf(c1.x); bx[5]=f2bf(c1.y); bx[6]=f2bf(c1.z); bx[7]=f2bf(c1.w);
    #pragma unroll
    for (int c = 0; c < 3; ++c){                 // A[m=outcol][k]: lane l31 = outcol
      s16x8 wa = *(const s16x8*)(Wt + (ch + c*32 + l31)*384 + s*16 + hh*8);
      acc[c] = __builtin_amdgcn_mfma_f32_32x32x16_bf16(wa, bx, acc[c], 0, 0, 0);
    }
    c0 = n0; c1 = n1;
  }

  // Epilogue: C col(n)=row=l31, m=(reg&3)+8*(reg>>2)+4*hh = outcol-within-frag
  #pragma unroll
  for (int c = 0; c < 3; ++c){
    const int n0 = ch + c*32;
    if (n0 < 128){                               // Q (0,32) / K (64,96): [t][h] bf16
      short* dst = (n0 < 64) ? (Q + trow*64 + n0) : (K + trow*64 + (n0 - 64));
      #pragma unroll
      for (int g = 0; g < 4; ++g){
        s16x4 v;
        #pragma unroll
        for (int i = 0; i < 4; ++i) v[i] = f2bf(acc[c][g*4 + i]);
        *(s16x4*)(dst + 8*g + 4*hh) = v;
      }
    } else {                                     // V -> Vt[b][h][t]
      short* vb = Vt + (trow >> 8)*16384 + (trow & 255);
      #pragma unroll
      for (int reg = 0; reg < 16; ++reg){
        const int h = (n0 - 128) + (reg & 3) + 8*(reg >> 2) + 4*hh;
        vb[h*256] = f2bf(acc[c][reg]);
      }
    }
  }
}

// ---------------- Kernel 2: causal attention (R2 verbatim — known good) -------
__global__ __launch_bounds__(256) void attn_kernel(const short* __restrict__ Q, const short* __restrict__ K,
                            const short* __restrict__ Vt, float* __restrict__ out){
  __shared__ __align__(16) short P[4][16*40];  // per-wave 16 x 32 chunk, stride 40
  const int tid  = threadIdx.x;
  const int w    = tid >> 6, lane = tid & 63;
  const int l15  = lane & 15, quad = lane >> 4;
  const int b    = blockIdx.x >> 2, qt = blockIdx.x & 3;
  const int qbase = qt*64 + w*16;
  const int NFw  = (qbase >> 4) + 1;           // causal key-frags needed (1..16)
  const int NSw  = (NFw + 1) >> 1;             // 32-key PV steps (1..8)

  const short* Qs = Q  + ((long)b*256 + qbase)*64;
  const short* Ks = K  + (long)b*256*64;
  const short* Vs = Vt + (long)b*64*256;

  // A frags: A[m=lane&15][k=(lane>>4)*8+j]
  s16x8 qf0 = *(const s16x8*)(Qs + l15*64 + quad*8);
  s16x8 qf1 = *(const s16x8*)(Qs + l15*64 + 32 + quad*8);

  f32x4 sc[16];
  #pragma unroll
  for (int f = 0; f < 16; ++f){
    f32x4 a;
    #pragma unroll
    for (int r = 0; r < 4; ++r) a[r] = 0.0f;
    if (f < NFw){
      const short* kp = Ks + (f*16 + l15)*64 + quad*8;   // B[k][n=key]
      s16x8 k0v = *(const s16x8*)kp;
      s16x8 k1v = *(const s16x8*)(kp + 32);
      a = __builtin_amdgcn_mfma_f32_16x16x32_bf16(qf0, k0v, a, 0, 0, 0);
      a = __builtin_amdgcn_mfma_f32_16x16x32_bf16(qf1, k1v, a, 0, 0, 0);
    }
    sc[f] = a;
  }

  // softmax: C col=key=f*16+(lane&15), row=query=quad*4+reg
  float mx[4], sm[4];
  #pragma unroll
  for (int r = 0; r < 4; ++r) mx[r] = -3.0e38f;
  #pragma unroll
  for (int f = 0; f < 16; ++f){
    if (f < NFw){
      const int key = f*16 + l15;
      #pragma unroll
      for (int r = 0; r < 4; ++r){
        const int qg = qbase + quad*4 + r;
        float s = sc[f][r] * 0.125f;               // d^-0.5, H=64
        s = (key <= qg) ? s : -1.0e30f;
        sc[f][r] = s;
        mx[r] = fmaxf(mx[r], s);
      }
    }
  }
  #pragma unroll
  for (int r = 0; r < 4; ++r){
    #pragma unroll
    for (int off = 1; off < 16; off <<= 1) mx[r] = fmaxf(mx[r], __shfl_xor(mx[r], off, 16));
  }
  #pragma unroll
  for (int r = 0; r < 4; ++r) sm[r] = 0.0f;
  #pragma unroll
  for (int f = 0; f < 16; ++f){
    if (f < NFw){
      #pragma unroll
      for (int r = 0; r < 4; ++r){
        float p = exp2f((sc[f][r] - mx[r]) * 1.44269504f);
        sc[f][r] = p;
        sm[r] += p;
      }
    }
  }
  #pragma unroll
  for (int r = 0; r < 4; ++r){
    #pragma unroll
    for (int off = 1; off < 16; off <<= 1) sm[r] += __shfl_xor(sm[r], off, 16);
  }

  // PV: out[16q x 64h], A = P via LDS round-trip, B = Vt rows
  f32x4 o[4];
  #pragma unroll
  for (int h = 0; h < 4; ++h)
    #pragma unroll
    for (int r = 0; r < 4; ++r) o[h][r] = 0.0f;

  short* Pw = P[w];
  #pragma unroll
  for (int ks = 0; ks < 8; ++ks){
    if (ks < NSw){
      #pragma unroll
      for (int fi = 0; fi < 2; ++fi){
        const int f = 2*ks + fi;
        #pragma unroll
        for (int r = 0; r < 4; ++r){
          short v = 0;
          if (f < NFw) v = f2bf(sc[f][r]);
          Pw[(quad*4 + r)*40 + fi*16 + l15] = v;
        }
      }
      s16x8 pf = *(const s16x8*)(Pw + l15*40 + quad*8);  // A[m=l15][k=quad*8+j]
      #pragma unroll
      for (int h = 0; h < 4; ++h){
        s16x8 vf = *(const s16x8*)(Vs + (h*16 + l15)*256 + ks*32 + quad*8);
        o[h] = __builtin_amdgcn_mfma_f32_16x16x32_bf16(pf, vf, o[h], 0, 0, 0);
      }
    }
  }

  float* op = out + ((long)b*256 + qbase)*64;
  #pragma unroll
  for (int r = 0; r < 4; ++r){
    const float inv = 1.0f / sm[r];
    #pragma unroll
    for (int h = 0; h < 4; ++h)
      op[(quad*4 + r)*64 + h*16 + l15] = o[h][r] * inv;
  }
}

extern "C" void kernel_launch(void* const* d_in, const int* in_sizes, int n_in,
                              void* d_out, int out_size, void* d_ws, size_t ws_size,
                              hipStream_t stream){
  const float* x  = (const float*)d_in[0];
  const float* Wq = (const float*)d_in[1];
  const float* Wk = (const float*)d_in[2];
  const float* Wv = (const float*)d_in[3];
  float* out = (float*)d_out;

  char* ws = (char*)d_ws;
  short* Wt = (short*)ws;                                  // 147456 B
  short* Q  = (short*)(ws + 147456);                       // 16.78 MB
  short* K  = (short*)(ws + 147456 + 16777216);
  short* Vt = (short*)(ws + 147456 + 2*16777216);          // [b][h][t]

  hipLaunchKernelGGL(wt_prep_kernel, dim3(288),  dim3(256), 0, stream, Wq, Wk, Wv, Wt);
  hipLaunchKernelGGL(proj_kernel,    dim3(2048), dim3(256), 0, stream, x, Wt, Q, K, Vt);
  hipLaunchKernelGGL(attn_kernel,    dim3(2048), dim3(256), 0, stream, Q, K, Vt, out);
}

// Round 6
// 392.999 us; speedup vs baseline: 1.2696x; 1.1934x over previous
//
#include <hip/hip_runtime.h>

typedef __attribute__((ext_vector_type(4)))  float f32x4;
typedef __attribute__((ext_vector_type(16))) float f32x16;
typedef __attribute__((ext_vector_type(8)))  short s16x8;
typedef __attribute__((ext_vector_type(4)))  short s16x4;

// B=512, T=256, E=384, H=64.  M = B*T = 131072 rows.

__device__ inline short f2bf(float f){
  unsigned u = __float_as_uint(f);
  u = u + 0x7fffu + ((u >> 16) & 1u);   // round-to-nearest-even
  return (short)(u >> 16);
}

// ---------------- Kernel 0: Wt[n][k] = W_{n/64}[k][n%64]  (bf16) ----------------
__global__ void wt_prep_kernel(const float* __restrict__ Wq, const float* __restrict__ Wk,
                               const float* __restrict__ Wv, short* __restrict__ Wt){
  int o = blockIdx.x * 256 + threadIdx.x;
  if (o >= 192*384) return;
  int n = o / 384, k = o - n*384;
  const float* W = (n < 64) ? Wq : (n < 128) ? Wk : Wv;
  Wt[o] = f2bf(W[k*64 + (n & 63)]);
}

// ---------------- Kernel 1: QKV projection v3 ----------------
// Full Wt resident in LDS (192 cols x stride 392 shorts = 150528 B), staged
// ONCE -> exactly one __syncthreads in the whole kernel; after it the K-loop
// is barrier-free so the x prefetch pipeline never drains (R2 drained vmcnt(0)
// 12x/block; R5 had no LDS but only ~1 step of load depth -> 0.77 TB/s).
// 1024 thr = 16 waves = 4 waves/SIMD (1 block/CU). Wave tile 32 rows x 96
// cols: acc[3] = 48 AGPR. Explicit 6-step rolling x prefetch (48 VGPR) = 12
// outstanding 16B loads/wave, flowing across both 256-row iterations.
#define PF 6
__global__ __launch_bounds__(1024, 4) void proj_kernel(const float* __restrict__ x,
                            const short* __restrict__ Wt,
                            short* __restrict__ Q, short* __restrict__ K,
                            short* __restrict__ Vt){
  __shared__ __align__(16) short Wl[192*392];    // stride 392 = 196 dw == 4 mod 32

  const int tid  = threadIdx.x;
  const int w    = tid >> 6, lane = tid & 63;
  const int l31  = lane & 31, hh = lane >> 5;
  const int ch   = (w & 1) * 96;                 // column half
  const int rg   = w >> 1;                       // row group 0..7
  const long rbase = (long)blockIdx.x*512 + rg*32 + l31;

  // Stage all of Wt into LDS: 9216 16B-chunks over 1024 threads = 9 iters.
  #pragma unroll
  for (int i = 0; i < 9; ++i){
    int c   = tid + i*1024;                      // 0..9215
    int col = c / 48, off = (c % 48)*8;
    *(s16x8*)(Wl + col*392 + off) = *(const s16x8*)(Wt + col*384 + off);
  }
  __syncthreads();                               // the ONLY barrier

  const float* xA = x + rbase*384 + hh*8;

  float4 buf[PF][2];
  #pragma unroll
  for (int p = 0; p < PF; ++p){
    buf[p][0] = *(const float4*)(xA + p*16);
    buf[p][1] = *(const float4*)(xA + p*16 + 4);
  }

  #pragma unroll
  for (int iter = 0; iter < 2; ++iter){
    const float* cur = xA + iter*(256*384);

    f32x16 acc[3];
    #pragma unroll
    for (int c = 0; c < 3; ++c)
      #pragma unroll
      for (int q = 0; q < 16; ++q) acc[c][q] = 0.0f;

    #pragma unroll
    for (int s = 0; s < 24; ++s){                // K-step of 16 (k = s*16 + hh*8 + j)
      float4 b0 = buf[s % PF][0], b1 = buf[s % PF][1];
      // rolling prefetch PF steps ahead (crosses into iter 1 seamlessly)
      if (iter == 0){
        const int g = s + PF;
        const float* src = (g < 24) ? (cur + g*16) : (cur + 256*384 + (g - 24)*16);
        buf[s % PF][0] = *(const float4*)src;
        buf[s % PF][1] = *(const float4*)(src + 4);
      } else if (s < 24 - PF){
        const float* src = cur + (s + PF)*16;
        buf[s % PF][0] = *(const float4*)src;
        buf[s % PF][1] = *(const float4*)(src + 4);
      }
      s16x8 bx;                                  // B[k][n=row]: lane l31 = row
      bx[0]=f2bf(b0.x); bx[1]=f2bf(b0.y); bx[2]=f2bf(b0.z); bx[3]=f2bf(b0.w);
      bx[4]=f2bf(b1.x); bx[5]=f2bf(b1.y); bx[6]=f2bf(b1.z); bx[7]=f2bf(b1.w);
      #pragma unroll
      for (int c = 0; c < 3; ++c){               // A[m=outcol][k] from LDS
        s16x8 wa = *(const s16x8*)(Wl + (ch + c*32 + l31)*392 + s*16 + hh*8);
        acc[c] = __builtin_amdgcn_mfma_f32_32x32x16_bf16(wa, bx, acc[c], 0, 0, 0);
      }
    }

    // Epilogue: C col(n)=row=l31, m=(reg&3)+8*(reg>>2)+4*hh = outcol-within-frag
    const long trow = rbase + iter*256;
    #pragma unroll
    for (int c = 0; c < 3; ++c){
      const int n0 = ch + c*32;
      if (n0 < 128){                             // Q (0,32) / K (64,96): [t][h]
        short* dst = (n0 < 64) ? (Q + trow*64 + n0) : (K + trow*64 + (n0 - 64));
        #pragma unroll
        for (int g = 0; g < 4; ++g){
          s16x4 v;
          #pragma unroll
          for (int i = 0; i < 4; ++i) v[i] = f2bf(acc[c][g*4 + i]);
          *(s16x4*)(dst + 8*g + 4*hh) = v;
        }
      } else {                                   // V -> Vt[b][h][t]
        short* vb = Vt + (trow >> 8)*16384 + (trow & 255);
        #pragma unroll
        for (int reg = 0; reg < 16; ++reg){
          const int h = (n0 - 128) + (reg & 3) + 8*(reg >> 2) + 4*hh;
          vb[h*256] = f2bf(acc[c][reg]);
        }
      }
    }
  }
}

// ---------------- Kernel 2: causal attention (R2 verbatim — known good) -------
__global__ __launch_bounds__(256) void attn_kernel(const short* __restrict__ Q, const short* __restrict__ K,
                            const short* __restrict__ Vt, float* __restrict__ out){
  __shared__ __align__(16) short P[4][16*40];  // per-wave 16 x 32 chunk, stride 40
  const int tid  = threadIdx.x;
  const int w    = tid >> 6, lane = tid & 63;
  const int l15  = lane & 15, quad = lane >> 4;
  const int b    = blockIdx.x >> 2, qt = blockIdx.x & 3;
  const int qbase = qt*64 + w*16;
  const int NFw  = (qbase >> 4) + 1;           // causal key-frags needed (1..16)
  const int NSw  = (NFw + 1) >> 1;             // 32-key PV steps (1..8)

  const short* Qs = Q  + ((long)b*256 + qbase)*64;
  const short* Ks = K  + (long)b*256*64;
  const short* Vs = Vt + (long)b*64*256;

  // A frags: A[m=lane&15][k=(lane>>4)*8+j]
  s16x8 qf0 = *(const s16x8*)(Qs + l15*64 + quad*8);
  s16x8 qf1 = *(const s16x8*)(Qs + l15*64 + 32 + quad*8);

  f32x4 sc[16];
  #pragma unroll
  for (int f = 0; f < 16; ++f){
    f32x4 a;
    #pragma unroll
    for (int r = 0; r < 4; ++r) a[r] = 0.0f;
    if (f < NFw){
      const short* kp = Ks + (f*16 + l15)*64 + quad*8;   // B[k][n=key]
      s16x8 k0v = *(const s16x8*)kp;
      s16x8 k1v = *(const s16x8*)(kp + 32);
      a = __builtin_amdgcn_mfma_f32_16x16x32_bf16(qf0, k0v, a, 0, 0, 0);
      a = __builtin_amdgcn_mfma_f32_16x16x32_bf16(qf1, k1v, a, 0, 0, 0);
    }
    sc[f] = a;
  }

  // softmax: C col=key=f*16+(lane&15), row=query=quad*4+reg
  float mx[4], sm[4];
  #pragma unroll
  for (int r = 0; r < 4; ++r) mx[r] = -3.0e38f;
  #pragma unroll
  for (int f = 0; f < 16; ++f){
    if (f < NFw){
      const int key = f*16 + l15;
      #pragma unroll
      for (int r = 0; r < 4; ++r){
        const int qg = qbase + quad*4 + r;
        float s = sc[f][r] * 0.125f;               // d^-0.5, H=64
        s = (key <= qg) ? s : -1.0e30f;
        sc[f][r] = s;
        mx[r] = fmaxf(mx[r], s);
      }
    }
  }
  #pragma unroll
  for (int r = 0; r < 4; ++r){
    #pragma unroll
    for (int off = 1; off < 16; off <<= 1) mx[r] = fmaxf(mx[r], __shfl_xor(mx[r], off, 16));
  }
  #pragma unroll
  for (int r = 0; r < 4; ++r) sm[r] = 0.0f;
  #pragma unroll
  for (int f = 0; f < 16; ++f){
    if (f < NFw){
      #pragma unroll
      for (int r = 0; r < 4; ++r){
        float p = exp2f((sc[f][r] - mx[r]) * 1.44269504f);
        sc[f][r] = p;
        sm[r] += p;
      }
    }
  }
  #pragma unroll
  for (int r = 0; r < 4; ++r){
    #pragma unroll
    for (int off = 1; off < 16; off <<= 1) sm[r] += __shfl_xor(sm[r], off, 16);
  }

  // PV: out[16q x 64h], A = P via LDS round-trip, B = Vt rows
  f32x4 o[4];
  #pragma unroll
  for (int h = 0; h < 4; ++h)
    #pragma unroll
    for (int r = 0; r < 4; ++r) o[h][r] = 0.0f;

  short* Pw = P[w];
  #pragma unroll
  for (int ks = 0; ks < 8; ++ks){
    if (ks < NSw){
      #pragma unroll
      for (int fi = 0; fi < 2; ++fi){
        const int f = 2*ks + fi;
        #pragma unroll
        for (int r = 0; r < 4; ++r){
          short v = 0;
          if (f < NFw) v = f2bf(sc[f][r]);
          Pw[(quad*4 + r)*40 + fi*16 + l15] = v;
        }
      }
      s16x8 pf = *(const s16x8*)(Pw + l15*40 + quad*8);  // A[m=l15][k=quad*8+j]
      #pragma unroll
      for (int h = 0; h < 4; ++h){
        s16x8 vf = *(const s16x8*)(Vs + (h*16 + l15)*256 + ks*32 + quad*8);
        o[h] = __builtin_amdgcn_mfma_f32_16x16x32_bf16(pf, vf, o[h], 0, 0, 0);
      }
    }
  }

  float* op = out + ((long)b*256 + qbase)*64;
  #pragma unroll
  for (int r = 0; r < 4; ++r){
    const float inv = 1.0f / sm[r];
    #pragma unroll
    for (int h = 0; h < 4; ++h)
      op[(quad*4 + r)*64 + h*16 + l15] = o[h][r] * inv;
  }
}

extern "C" void kernel_launch(void* const* d_in, const int* in_sizes, int n_in,
                              void* d_out, int out_size, void* d_ws, size_t ws_size,
                              hipStream_t stream){
  const float* x  = (const float*)d_in[0];
  const float* Wq = (const float*)d_in[1];
  const float* Wk = (const float*)d_in[2];
  const float* Wv = (const float*)d_in[3];
  float* out = (float*)d_out;

  char* ws = (char*)d_ws;
  short* Wt = (short*)ws;                                  // 147456 B
  short* Q  = (short*)(ws + 147456);                       // 16.78 MB
  short* K  = (short*)(ws + 147456 + 16777216);
  short* Vt = (short*)(ws + 147456 + 2*16777216);          // [b][h][t]

  hipLaunchKernelGGL(wt_prep_kernel, dim3(288),  dim3(256), 0, stream, Wq, Wk, Wv, Wt);
  hipLaunchKernelGGL(proj_kernel,    dim3(256),  dim3(1024), 0, stream, x, Wt, Q, K, Vt);
  hipLaunchKernelGGL(attn_kernel,    dim3(2048), dim3(256), 0, stream, Q, K, Vt, out);
}